// Round 22
// baseline (127.896 us; speedup 1.0000x reference)
//
#include <hip/hip_runtime.h>
#include <math.h>

#define FRAME_LEN 400
#define NBINS 257
#define NMEL 80
#define MEL_FLOOR 1.192092955078125e-07f

constexpr int B = 16;
constexpr int T = 480000;
constexpr int F = 1 + (T - FRAME_LEN) / 160; // 2998
constexpr int FRB = 16;                       // frames per block (8 waves x 2 frames)
constexpr int BPB = (F + FRB - 1) / FRB;      // 188 blocks per batch
constexpr int NBLK = B * BPB;                 // 3008

// ws float offsets
#define WS_TW256C 0      // 256
#define WS_TW256S 256
#define WS_TW64C  512    // 32
#define WS_TW64S  544
#define WS_UNP4C  576    // float4[64]
#define WS_UNP4S  832
#define WS_K0     1088   // int[80]
#define WS_LEN    1168   // int[80]
#define WS_WGT    1280   // float[32*80] -> ends 3840
#define WS_ACC    3840   // float[16][2][80] atomic accumulators -> ends 6400
#define WS_STAT   6400   // float[16][2][80] mean/invstd -> ends 8960
#define WS_PART   9216   // float[3008][2][80] = 481280 -> ends 490496
constexpr size_t WS_NEED_PART = (size_t)(WS_PART + NBLK * 160) * 4;

__device__ __forceinline__ int brev6(int x) { return (int)(__brev((unsigned)x) >> 26); }
__device__ __forceinline__ int specIdx(int k) { return k + ((k >> 5) << 2); }

// ---------------- Kernel 0: build tables + zero atomic accumulators ----------------
__global__ __launch_bounds__(256) void setup_kernel(
    const float* __restrict__ fil, float* __restrict__ ws)
{
    const int t = threadIdx.x;
    float s, c;
    sincosf(-6.283185307179586f * (float)t / 256.0f, &s, &c);
    ws[WS_TW256C + t] = c; ws[WS_TW256S + t] = s;
    if (t < 32) {
        sincosf(-6.283185307179586f * (float)t / 64.0f, &s, &c);
        ws[WS_TW64C + t] = c; ws[WS_TW64S + t] = s;
    }
    if (t < 64) {
        int m = brev6(t);
        for (int j = 0; j < 4; ++j) {
            sincosf(-6.283185307179586f * (float)(4 * m + j) / 512.0f, &s, &c);
            ws[WS_UNP4C + 4 * t + j] = c;
            ws[WS_UNP4S + 4 * t + j] = s;
        }
    }
    for (int i = t; i < 2560; i += 256) ws[WS_ACC + i] = 0.0f;  // zero accumulators
    // sparse mel compaction
    __shared__ int sh_k0[3][NMEL], sh_k1[3][NMEL];
    __shared__ int sh_K0[NMEL], sh_LEN[NMEL];
    if (t < 240) {
        int m = t % NMEL, r = t / NMEL;
        int kb = r * 86, ke = (kb + 86 < NBINS) ? (kb + 86) : NBINS;
        int k0 = -1, k1 = -1;
        for (int k = kb; k < ke; ++k) {
            if (fil[k * NMEL + m] > 0.0f) { if (k0 < 0) k0 = k; k1 = k; }
        }
        sh_k0[r][m] = k0; sh_k1[r][m] = k1;
    }
    __syncthreads();
    if (t < NMEL) {
        int k0 = -1, k1 = -1;
        for (int r = 0; r < 3; ++r) {
            int a = sh_k0[r][t], b1 = sh_k1[r][t];
            if (a >= 0) { if (k0 < 0) k0 = a; k1 = b1; }
        }
        int len = (k0 < 0) ? 0 : (k1 - k0 + 1);
        if (len > 32) len = 32;
        if (k0 < 0) k0 = 0;
        ((int*)ws)[WS_K0 + t] = k0;
        ((int*)ws)[WS_LEN + t] = len;
        sh_K0[t] = k0; sh_LEN[t] = len;
    }
    __syncthreads();
    for (int idx = t; idx < 32 * NMEL; idx += 256) {
        int j = idx / NMEL, m = idx - j * NMEL;
        ws[WS_WGT + idx] = (j < sh_LEN[m]) ? fil[(sh_K0[m] + j) * NMEL + m] : 0.0f;
    }
}

// ---------------- Kernel 1: 2 frames/wave, 16 frames/block, LDS-atomic fused stats ----------------
__global__ __launch_bounds__(512, 6) void frame_logmel_kernel(
    const float* __restrict__ wav,
    const float* __restrict__ win,
    float* __restrict__ ws,
    float* __restrict__ mel_out,
    int partMode)
{
    __shared__ float s_t256c[256], s_t256s[256];
    __shared__ float s_t64c[32], s_t64s[32];
    __shared__ float4 s_upc[64], s_ups[64];
    __shared__ float s_wgt[32 * NMEL];
    __shared__ int s_k0[NMEL], s_len[NMEL];
    __shared__ float2 s_win2[200];
    __shared__ float s_spec[FRB][296];
    __shared__ float s_acc[160], s_acc2[160];

    const int t = threadIdx.x;
    if (t < 256) {
        s_t256c[t] = ws[WS_TW256C + t];
        s_t256s[t] = ws[WS_TW256S + t];
    }
    if (t < 32) { s_t64c[t] = ws[WS_TW64C + t]; s_t64s[t] = ws[WS_TW64S + t]; }
    if (t < 64) {
        s_upc[t] = ((const float4*)(ws + WS_UNP4C))[t];
        s_ups[t] = ((const float4*)(ws + WS_UNP4S))[t];
    }
    for (int i = t; i < 32 * NMEL; i += 512) s_wgt[i] = ws[WS_WGT + i];
    if (t < NMEL) { s_k0[t] = ((const int*)ws)[WS_K0 + t]; s_len[t] = ((const int*)ws)[WS_LEN + t]; }
    if (t < 200) s_win2[t] = ((const float2*)win)[t];
    if (t >= 256 && t < 416) { s_acc[t - 256] = 0.0f; s_acc2[t - 256] = 0.0f; }
    __syncthreads();  // tables ready + accumulators zeroed

    const int l = t & 63, w = t >> 6;
    const int bid = blockIdx.x;
    const int b = bid / BPB, blk = bid - b * BPB;
    int fidx[2];
    bool live[2];
    const float2* src[2];
    #pragma unroll
    for (int ff = 0; ff < 2; ++ff) {
        fidx[ff] = blk * FRB + w * 2 + ff;
        live[ff] = (fidx[ff] < F);
        src[ff] = (const float2*)(wav + (size_t)b * T + (size_t)(live[ff] ? fidx[ff] : 0) * 160);
    }

    // load frames (complex-packed pairs), per-wave means (interleaved)
    float xr[2][4], xi[2][4];
    float sum[2] = {0.0f, 0.0f};
    #pragma unroll
    for (int ff = 0; ff < 2; ++ff) {
        #pragma unroll
        for (int j = 0; j < 4; ++j) {
            int p = 64 * j + l;
            float2 v = (live[ff] && p < 200) ? src[ff][p] : make_float2(0.0f, 0.0f);
            xr[ff][j] = v.x * 32768.0f;
            xi[ff][j] = v.y * 32768.0f;
            sum[ff] += xr[ff][j] + xi[ff][j];
        }
    }
    #pragma unroll
    for (int m = 32; m >= 1; m >>= 1) {
        sum[0] += __shfl_xor(sum[0], m);
        sum[1] += __shfl_xor(sum[1], m);
    }
    float mean[2] = {sum[0] * (1.0f / 400.0f), sum[1] * (1.0f / 400.0f)};

    // preemphasis + window
    float ur[2][4], ui[2][4];
    #pragma unroll
    for (int ff = 0; ff < 2; ++ff) {
        float zr[4], zi[4];
        float carry = 0.0f;
        #pragma unroll
        for (int j = 0; j < 4; ++j) {
            float y = xi[ff][j], x0 = xr[ff][j];
            float up = __shfl(y, (l + 63) & 63);
            float nc = __shfl(y, 63);
            if (l == 0) up = (j == 0) ? x0 : carry;
            carry = nc;
            int p = 64 * j + l;
            float2 w2 = (p < 200) ? s_win2[p] : make_float2(0.0f, 0.0f);
            zr[j] = (x0 - 0.97f * up - 0.03f * mean[ff]) * w2.x;
            zi[j] = (y - 0.97f * x0 - 0.03f * mean[ff]) * w2.y;
        }
        // in-lane radix-4 first stage
        float Ar = zr[0] + zr[2], Ai = zi[0] + zi[2];
        float Br = zr[0] - zr[2], Bi = zi[0] - zi[2];
        float Cr = zr[1] + zr[3], Ci = zi[1] + zi[3];
        float Dr = zr[1] - zr[3], Di = zi[1] - zi[3];
        ur[ff][0] = Ar + Cr; ui[ff][0] = Ai + Ci;
        ur[ff][1] = Br + Di; ui[ff][1] = Bi - Dr;
        ur[ff][2] = Ar - Cr; ui[ff][2] = Ai - Ci;
        ur[ff][3] = Br - Di; ui[ff][3] = Bi + Dr;
    }
    // W_256^{j*l} twiddles (both frames interleaved)
    {
        float w1r = s_t256c[l],     w1i = s_t256s[l];
        float w2r = s_t256c[2 * l], w2i = s_t256s[2 * l];
        float w3r = s_t256c[3 * l], w3i = s_t256s[3 * l];
        #pragma unroll
        for (int ff = 0; ff < 2; ++ff) {
            float tr;
            tr = ur[ff][1] * w1r - ui[ff][1] * w1i; ui[ff][1] = ur[ff][1] * w1i + ui[ff][1] * w1r; ur[ff][1] = tr;
            tr = ur[ff][2] * w2r - ui[ff][2] * w2i; ui[ff][2] = ur[ff][2] * w2i + ui[ff][2] * w2r; ur[ff][2] = tr;
            tr = ur[ff][3] * w3r - ui[ff][3] * w3i; ui[ff][3] = ur[ff][3] * w3i + ui[ff][3] * w3r; ur[ff][3] = tr;
        }
    }

    // 64-pt FFT across lanes, 2 frames x 4 values interleaved (8-way ILP)
    #pragma unroll
    for (int h = 32; h >= 1; h >>= 1) {
        int idx = (l & (h - 1)) * (32 / h);
        bool hi = (l & h) != 0;
        float wr = hi ? s_t64c[idx] : 1.0f;
        float wi = hi ? s_t64s[idx] : 0.0f;
        float sg = hi ? -1.0f : 1.0f;
        #pragma unroll
        for (int ff = 0; ff < 2; ++ff) {
            #pragma unroll
            for (int v = 0; v < 4; ++v) {
                float pr = __shfl_xor(ur[ff][v], h), pi = __shfl_xor(ui[ff][v], h);
                float sr = fmaf(sg, ur[ff][v], pr), si = fmaf(sg, ui[ff][v], pi);
                ur[ff][v] = sr * wr - si * wi;
                ui[ff][v] = sr * wi + si * wr;
            }
        }
    }

    // real-FFT unpack in-register, power spectrum (per frame)
    const int m = brev6(l);
    const int l0 = brev6((64 - m) & 63);
    const float4 wc = s_upc[l], wn = s_ups[l];
    #pragma unroll
    for (int ff = 0; ff < 2; ++ff) {
        float b1r = __shfl_xor(ur[ff][3], 63), b1i = __shfl_xor(ui[ff][3], 63);
        float b2r = __shfl_xor(ur[ff][2], 63), b2i = __shfl_xor(ui[ff][2], 63);
        float b3r = __shfl_xor(ur[ff][1], 63), b3i = __shfl_xor(ui[ff][1], 63);
        float b0r = __shfl(ur[ff][0], l0), b0i = __shfl(ui[ff][0], l0);
        float sp[4];
        #define UNP(J, ar, ai, br, bi, twr, twi)                        \
        {                                                               \
            float Er = 0.5f * (ar + br), Ei = 0.5f * (ai - bi);         \
            float Or = 0.5f * (ai + bi), Oi = 0.5f * (br - ar);         \
            float Xr = Er + twr * Or - twi * Oi;                        \
            float Xi = Ei + twr * Oi + twi * Or;                        \
            sp[J] = Xr * Xr + Xi * Xi;                                  \
        }
        UNP(0, ur[ff][0], ui[ff][0], b0r, b0i, wc.x, wn.x)
        UNP(1, ur[ff][1], ui[ff][1], b1r, b1i, wc.y, wn.y)
        UNP(2, ur[ff][2], ui[ff][2], b2r, b2i, wc.z, wn.z)
        UNP(3, ur[ff][3], ui[ff][3], b3r, b3i, wc.w, wn.w)
        #undef UNP
        ((float4*)s_spec[w * 2 + ff])[m + (m >> 3)] = make_float4(sp[0], sp[1], sp[2], sp[3]);
        if (l == 0) {
            float d = ur[ff][0] - ui[ff][0];  // X[256] = Re(Z0) - Im(Z0)
            s_spec[w * 2 + ff][specIdx(256)] = d * d;
        }
    }

    // sparse mel projection (wave-private spec) + per-lane 2-frame stats pre-merge
    const int q = l & 3;
    float a0s = 0.0f, a0q = 0.0f;   // narrow mel l
    float a1s = 0.0f, a1q = 0.0f;   // wide mel 64+(l>>2), valid on q==0
    #pragma unroll
    for (int ff = 0; ff < 2; ++ff) {
        const int fr = w * 2 + ff;
        const size_t outbase = (size_t)(b * F + fidx[ff]) * NMEL;
        // narrow mels 0..63: one lane per mel
        {
            int mel = l;
            int k0 = s_k0[mel], len = s_len[mel];
            float acc = 0.0f;
            for (int i = 0; i < len; ++i)
                acc = fmaf(s_spec[fr][specIdx(k0 + i)], s_wgt[i * NMEL + mel], acc);
            float mv0 = __logf(fmaxf(acc, MEL_FLOOR));
            if (live[ff]) {
                mel_out[outbase + l] = mv0;
                a0s += mv0;
                a0q += mv0 * mv0;
            }
        }
        // wide mels 64..79: 4 lanes per mel, shfl-combine
        {
            int mel = 64 + (l >> 2);
            int k0 = s_k0[mel], len = s_len[mel];
            float acc = 0.0f;
            for (int i = q; i < len; i += 4)
                acc = fmaf(s_spec[fr][specIdx(k0 + i)], s_wgt[i * NMEL + mel], acc);
            acc += __shfl_xor(acc, 1);
            acc += __shfl_xor(acc, 2);
            if (q == 0) {
                float mv1 = __logf(fmaxf(acc, MEL_FLOOR));
                if (live[ff]) {
                    mel_out[outbase + mel] = mv1;
                    a1s += mv1;
                    a1q += mv1 * mv1;
                }
            }
        }
    }
    // LDS-atomic block accumulation (8-way contention max)
    atomicAdd(&s_acc[l], a0s);
    atomicAdd(&s_acc2[l], a0q);
    if (q == 0) {
        atomicAdd(&s_acc[64 + (l >> 2)], a1s);
        atomicAdd(&s_acc2[64 + (l >> 2)], a1q);
    }
    __syncthreads();
    if (t < 160) {
        float s = (t < 80) ? s_acc[t] : s_acc2[t - 80];
        if (partMode)
            ws[WS_PART + (size_t)bid * 160 + t] = s;
        else
            atomicAdd(&ws[WS_ACC + b * 160 + t], s);
    }
}

// ---------------- Kernel 2: finalize stats (parallel over 8 rows) ----------------
__global__ __launch_bounds__(640) void stats_final_kernel(float* __restrict__ ws, int partMode)
{
    const int b = blockIdx.x;
    const int m = threadIdx.x;   // 0..79
    const int r = threadIdx.y;   // 0..7
    __shared__ float shs[8][NMEL], shs2[8][NMEL];
    float s = 0.0f, s2 = 0.0f;
    if (partMode) {
        for (int c = r; c < BPB; c += 8) {
            const float* base = ws + WS_PART + (size_t)(b * BPB + c) * 160;
            s += base[m];
            s2 += base[80 + m];
        }
    }
    shs[r][m] = s; shs2[r][m] = s2;
    __syncthreads();
    if (r == 0) {
        double ds = 0.0, ds2 = 0.0;
        if (partMode) {
            #pragma unroll
            for (int i = 0; i < 8; ++i) { ds += (double)shs[i][m]; ds2 += (double)shs2[i][m]; }
        } else {
            ds = (double)ws[WS_ACC + b * 160 + m];
            ds2 = (double)ws[WS_ACC + b * 160 + 80 + m];
        }
        double mean = ds / (double)F;
        double var = (ds2 - ds * ds / (double)F) / (double)(F - 1);
        ws[WS_STAT + b * 160 + m] = (float)mean;
        ws[WS_STAT + b * 160 + 80 + m] = (float)(1.0 / sqrt(var + 1e-7));
    }
}

// ---------------- Kernel 3: normalize (float4) + mask ----------------
__global__ __launch_bounds__(256) void norm_mask_kernel(
    float* __restrict__ out, const float* __restrict__ ws)
{
    const float* stat = ws + WS_STAT;
    const int total4 = (B * F * NMEL) / 4;
    const int stride = gridDim.x * blockDim.x;
    float4* out4 = (float4*)out;
    for (int e4 = blockIdx.x * blockDim.x + threadIdx.x; e4 < total4; e4 += stride) {
        int e = e4 * 4;
        int b = e / (F * NMEL);
        int m = e % NMEL;
        const float* sb = stat + b * 160;
        float4 v = out4[e4];
        v.x = (v.x - sb[m + 0]) * sb[80 + m + 0];
        v.y = (v.y - sb[m + 1]) * sb[80 + m + 1];
        v.z = (v.z - sb[m + 2]) * sb[80 + m + 2];
        v.w = (v.w - sb[m + 3]) * sb[80 + m + 3];
        out4[e4] = v;
    }
    const int nmask = B * (F / 2);
    float* mask = out + (size_t)B * F * NMEL;
    for (int e = blockIdx.x * blockDim.x + threadIdx.x; e < nmask; e += stride)
        mask[e] = 1.0f;
}

extern "C" void kernel_launch(void* const* d_in, const int* in_sizes, int n_in,
                              void* d_out, int out_size, void* d_ws, size_t ws_size,
                              hipStream_t stream) {
    const float* wav = (const float*)d_in[0];
    const float* fil = (const float*)d_in[1];
    const float* win = (const float*)d_in[2];
    float* out = (float*)d_out;
    float* ws = (float*)d_ws;

    const int partMode = (ws_size >= WS_NEED_PART) ? 1 : 0;

    setup_kernel<<<1, 256, 0, stream>>>(fil, ws);
    frame_logmel_kernel<<<NBLK, 512, 0, stream>>>(wav, win, ws, out, partMode);
    stats_final_kernel<<<B, dim3(NMEL, 8), 0, stream>>>(ws, partMode);
    norm_mask_kernel<<<2048, 256, 0, stream>>>(out, ws);
}

// Round 25
// 110.987 us; speedup vs baseline: 1.1523x; 1.1523x over previous
//
#include <hip/hip_runtime.h>
#include <math.h>

#define FRAME_LEN 400
#define NBINS 257
#define NMEL 80
#define MEL_FLOOR 1.192092955078125e-07f

constexpr int B = 16;
constexpr int T = 480000;
constexpr int F = 1 + (T - FRAME_LEN) / 160; // 2998
constexpr int FRB = 16;                       // frames per block (8 waves x 2 frames)
constexpr int BPB = (F + FRB - 1) / FRB;      // 188 blocks per batch
constexpr int NBLK = B * BPB;                 // 3008

// ws float offsets
#define WS_TW256C 0      // 256
#define WS_TW256S 256
#define WS_TW64C  512    // 32
#define WS_TW64S  544
#define WS_UNP4C  576    // float4[64]
#define WS_UNP4S  832
#define WS_K0     1088   // int[80]
#define WS_LEN    1168   // int[80]
#define WS_WGT    1280   // float[32*80] -> ends 3840
#define WS_ACC    3840   // float[16][2][80] atomic accumulators -> ends 6400
#define WS_STAT   6400   // float[16][2][80] mean/invstd -> ends 8960
#define WS_PART   9216   // float[3008][2][80] = 481280 -> ends 490496
constexpr size_t WS_NEED_PART = (size_t)(WS_PART + NBLK * 160) * 4;

__device__ __forceinline__ int brev6(int x) { return (int)(__brev((unsigned)x) >> 26); }
__device__ __forceinline__ int specIdx(int k) { return k + ((k >> 5) << 2); }

// ---------------- Kernel 0: build tables + zero atomic accumulators ----------------
__global__ __launch_bounds__(256) void setup_kernel(
    const float* __restrict__ fil, float* __restrict__ ws)
{
    const int t = threadIdx.x;
    float s, c;
    sincosf(-6.283185307179586f * (float)t / 256.0f, &s, &c);
    ws[WS_TW256C + t] = c; ws[WS_TW256S + t] = s;
    if (t < 32) {
        sincosf(-6.283185307179586f * (float)t / 64.0f, &s, &c);
        ws[WS_TW64C + t] = c; ws[WS_TW64S + t] = s;
    }
    if (t < 64) {
        int m = brev6(t);
        for (int j = 0; j < 4; ++j) {
            sincosf(-6.283185307179586f * (float)(4 * m + j) / 512.0f, &s, &c);
            ws[WS_UNP4C + 4 * t + j] = c;
            ws[WS_UNP4S + 4 * t + j] = s;
        }
    }
    for (int i = t; i < 2560; i += 256) ws[WS_ACC + i] = 0.0f;  // zero accumulators
    // sparse mel compaction
    __shared__ int sh_k0[3][NMEL], sh_k1[3][NMEL];
    __shared__ int sh_K0[NMEL], sh_LEN[NMEL];
    if (t < 240) {
        int m = t % NMEL, r = t / NMEL;
        int kb = r * 86, ke = (kb + 86 < NBINS) ? (kb + 86) : NBINS;
        int k0 = -1, k1 = -1;
        for (int k = kb; k < ke; ++k) {
            if (fil[k * NMEL + m] > 0.0f) { if (k0 < 0) k0 = k; k1 = k; }
        }
        sh_k0[r][m] = k0; sh_k1[r][m] = k1;
    }
    __syncthreads();
    if (t < NMEL) {
        int k0 = -1, k1 = -1;
        for (int r = 0; r < 3; ++r) {
            int a = sh_k0[r][t], b1 = sh_k1[r][t];
            if (a >= 0) { if (k0 < 0) k0 = a; k1 = b1; }
        }
        int len = (k0 < 0) ? 0 : (k1 - k0 + 1);
        if (len > 32) len = 32;
        if (k0 < 0) k0 = 0;
        ((int*)ws)[WS_K0 + t] = k0;
        ((int*)ws)[WS_LEN + t] = len;
        sh_K0[t] = k0; sh_LEN[t] = len;
    }
    __syncthreads();
    for (int idx = t; idx < 32 * NMEL; idx += 256) {
        int j = idx / NMEL, m = idx - j * NMEL;
        ws[WS_WGT + idx] = (j < sh_LEN[m]) ? fil[(sh_K0[m] + j) * NMEL + m] : 0.0f;
    }
}

// ---------------- Kernel 1: 2 frames per wave (ILP), 16 frames/block + fused stats ----------------
__global__ __launch_bounds__(512, 6) void frame_logmel_kernel(
    const float* __restrict__ wav,
    const float* __restrict__ win,
    float* __restrict__ ws,
    float* __restrict__ mel_out,
    int partMode)
{
    __shared__ float s_t256c[256], s_t256s[256];
    __shared__ float s_t64c[32], s_t64s[32];
    __shared__ float4 s_upc[64], s_ups[64];
    __shared__ float s_wgt[32 * NMEL];
    __shared__ int s_k0[NMEL], s_len[NMEL];
    __shared__ float2 s_win2[200];
    __shared__ float s_spec[FRB][296];
    __shared__ float s_ss[FRB][NMEL], s_ss2[FRB][NMEL];

    const int t = threadIdx.x;
    if (t < 256) {
        s_t256c[t] = ws[WS_TW256C + t];
        s_t256s[t] = ws[WS_TW256S + t];
    }
    if (t < 32) { s_t64c[t] = ws[WS_TW64C + t]; s_t64s[t] = ws[WS_TW64S + t]; }
    if (t < 64) {
        s_upc[t] = ((const float4*)(ws + WS_UNP4C))[t];
        s_ups[t] = ((const float4*)(ws + WS_UNP4S))[t];
    }
    for (int i = t; i < 32 * NMEL; i += 512) s_wgt[i] = ws[WS_WGT + i];
    if (t < NMEL) { s_k0[t] = ((const int*)ws)[WS_K0 + t]; s_len[t] = ((const int*)ws)[WS_LEN + t]; }
    if (t < 200) s_win2[t] = ((const float2*)win)[t];
    __syncthreads();  // tables ready

    const int l = t & 63, w = t >> 6;
    const int bid = blockIdx.x;
    const int b = bid / BPB, blk = bid - b * BPB;
    int fidx[2];
    bool live[2];
    const float2* src[2];
    #pragma unroll
    for (int ff = 0; ff < 2; ++ff) {
        fidx[ff] = blk * FRB + w * 2 + ff;
        live[ff] = (fidx[ff] < F);
        src[ff] = (const float2*)(wav + (size_t)b * T + (size_t)(live[ff] ? fidx[ff] : 0) * 160);
    }

    // load frames (complex-packed pairs), per-wave means (interleaved)
    float xr[2][4], xi[2][4];
    float sum[2] = {0.0f, 0.0f};
    #pragma unroll
    for (int ff = 0; ff < 2; ++ff) {
        #pragma unroll
        for (int j = 0; j < 4; ++j) {
            int p = 64 * j + l;
            float2 v = (live[ff] && p < 200) ? src[ff][p] : make_float2(0.0f, 0.0f);
            xr[ff][j] = v.x * 32768.0f;
            xi[ff][j] = v.y * 32768.0f;
            sum[ff] += xr[ff][j] + xi[ff][j];
        }
    }
    #pragma unroll
    for (int m = 32; m >= 1; m >>= 1) {
        sum[0] += __shfl_xor(sum[0], m);
        sum[1] += __shfl_xor(sum[1], m);
    }
    float mean[2] = {sum[0] * (1.0f / 400.0f), sum[1] * (1.0f / 400.0f)};

    // preemphasis + window
    float ur[2][4], ui[2][4];
    #pragma unroll
    for (int ff = 0; ff < 2; ++ff) {
        float zr[4], zi[4];
        float carry = 0.0f;
        #pragma unroll
        for (int j = 0; j < 4; ++j) {
            float y = xi[ff][j], x0 = xr[ff][j];
            float up = __shfl(y, (l + 63) & 63);
            float nc = __shfl(y, 63);
            if (l == 0) up = (j == 0) ? x0 : carry;
            carry = nc;
            int p = 64 * j + l;
            float2 w2 = (p < 200) ? s_win2[p] : make_float2(0.0f, 0.0f);
            zr[j] = (x0 - 0.97f * up - 0.03f * mean[ff]) * w2.x;
            zi[j] = (y - 0.97f * x0 - 0.03f * mean[ff]) * w2.y;
        }
        // in-lane radix-4 first stage
        float Ar = zr[0] + zr[2], Ai = zi[0] + zi[2];
        float Br = zr[0] - zr[2], Bi = zi[0] - zi[2];
        float Cr = zr[1] + zr[3], Ci = zi[1] + zi[3];
        float Dr = zr[1] - zr[3], Di = zi[1] - zi[3];
        ur[ff][0] = Ar + Cr; ui[ff][0] = Ai + Ci;
        ur[ff][1] = Br + Di; ui[ff][1] = Bi - Dr;
        ur[ff][2] = Ar - Cr; ui[ff][2] = Ai - Ci;
        ur[ff][3] = Br - Di; ui[ff][3] = Bi + Dr;
    }
    // W_256^{j*l} twiddles (both frames interleaved)
    {
        float w1r = s_t256c[l],     w1i = s_t256s[l];
        float w2r = s_t256c[2 * l], w2i = s_t256s[2 * l];
        float w3r = s_t256c[3 * l], w3i = s_t256s[3 * l];
        #pragma unroll
        for (int ff = 0; ff < 2; ++ff) {
            float tr;
            tr = ur[ff][1] * w1r - ui[ff][1] * w1i; ui[ff][1] = ur[ff][1] * w1i + ui[ff][1] * w1r; ur[ff][1] = tr;
            tr = ur[ff][2] * w2r - ui[ff][2] * w2i; ui[ff][2] = ur[ff][2] * w2i + ui[ff][2] * w2r; ur[ff][2] = tr;
            tr = ur[ff][3] * w3r - ui[ff][3] * w3i; ui[ff][3] = ur[ff][3] * w3i + ui[ff][3] * w3r; ur[ff][3] = tr;
        }
    }

    // 64-pt FFT across lanes, 2 frames x 4 values interleaved (8-way ILP)
    #pragma unroll
    for (int h = 32; h >= 1; h >>= 1) {
        int idx = (l & (h - 1)) * (32 / h);
        bool hi = (l & h) != 0;
        float wr = hi ? s_t64c[idx] : 1.0f;
        float wi = hi ? s_t64s[idx] : 0.0f;
        float sg = hi ? -1.0f : 1.0f;
        #pragma unroll
        for (int ff = 0; ff < 2; ++ff) {
            #pragma unroll
            for (int v = 0; v < 4; ++v) {
                float pr = __shfl_xor(ur[ff][v], h), pi = __shfl_xor(ui[ff][v], h);
                float sr = fmaf(sg, ur[ff][v], pr), si = fmaf(sg, ui[ff][v], pi);
                ur[ff][v] = sr * wr - si * wi;
                ui[ff][v] = sr * wi + si * wr;
            }
        }
    }

    // real-FFT unpack in-register, power spectrum (per frame)
    const int m = brev6(l);
    const int l0 = brev6((64 - m) & 63);
    const float4 wc = s_upc[l], wn = s_ups[l];
    #pragma unroll
    for (int ff = 0; ff < 2; ++ff) {
        float b1r = __shfl_xor(ur[ff][3], 63), b1i = __shfl_xor(ui[ff][3], 63);
        float b2r = __shfl_xor(ur[ff][2], 63), b2i = __shfl_xor(ui[ff][2], 63);
        float b3r = __shfl_xor(ur[ff][1], 63), b3i = __shfl_xor(ui[ff][1], 63);
        float b0r = __shfl(ur[ff][0], l0), b0i = __shfl(ui[ff][0], l0);
        float sp[4];
        #define UNP(J, ar, ai, br, bi, twr, twi)                        \
        {                                                               \
            float Er = 0.5f * (ar + br), Ei = 0.5f * (ai - bi);         \
            float Or = 0.5f * (ai + bi), Oi = 0.5f * (br - ar);         \
            float Xr = Er + twr * Or - twi * Oi;                        \
            float Xi = Ei + twr * Oi + twi * Or;                        \
            sp[J] = Xr * Xr + Xi * Xi;                                  \
        }
        UNP(0, ur[ff][0], ui[ff][0], b0r, b0i, wc.x, wn.x)
        UNP(1, ur[ff][1], ui[ff][1], b1r, b1i, wc.y, wn.y)
        UNP(2, ur[ff][2], ui[ff][2], b2r, b2i, wc.z, wn.z)
        UNP(3, ur[ff][3], ui[ff][3], b3r, b3i, wc.w, wn.w)
        #undef UNP
        ((float4*)s_spec[w * 2 + ff])[m + (m >> 3)] = make_float4(sp[0], sp[1], sp[2], sp[3]);
        if (l == 0) {
            float d = ur[ff][0] - ui[ff][0];  // X[256] = Re(Z0) - Im(Z0)
            s_spec[w * 2 + ff][specIdx(256)] = d * d;
        }
    }

    // sparse mel projection (wave-private spec; no barrier needed)
    const int q = l & 3;
    #pragma unroll
    for (int ff = 0; ff < 2; ++ff) {
        const int fr = w * 2 + ff;
        const size_t outbase = (size_t)(b * F + fidx[ff]) * NMEL;
        // narrow mels 0..63: one lane per mel
        float mv0;
        {
            int mel = l;
            int k0 = s_k0[mel], len = s_len[mel];
            float acc = 0.0f;
            for (int i = 0; i < len; ++i)
                acc = fmaf(s_spec[fr][specIdx(k0 + i)], s_wgt[i * NMEL + mel], acc);
            mv0 = __logf(fmaxf(acc, MEL_FLOOR));
            if (live[ff]) mel_out[outbase + l] = mv0;
        }
        // wide mels 64..79: 4 lanes per mel, shfl-combine
        float mv1 = 0.0f;
        {
            int mel = 64 + (l >> 2);
            int k0 = s_k0[mel], len = s_len[mel];
            float acc = 0.0f;
            for (int i = q; i < len; i += 4)
                acc = fmaf(s_spec[fr][specIdx(k0 + i)], s_wgt[i * NMEL + mel], acc);
            acc += __shfl_xor(acc, 1);
            acc += __shfl_xor(acc, 2);
            if (q == 0) {
                mv1 = __logf(fmaxf(acc, MEL_FLOOR));
                if (live[ff]) mel_out[outbase + mel] = mv1;
            }
        }
        // stats partial stage
        float v0 = live[ff] ? mv0 : 0.0f;
        s_ss[fr][l] = v0;
        s_ss2[fr][l] = v0 * v0;
        if (q == 0) {
            float v1 = live[ff] ? mv1 : 0.0f;
            s_ss[fr][64 + (l >> 2)] = v1;
            s_ss2[fr][64 + (l >> 2)] = v1 * v1;
        }
    }
    __syncthreads();
    if (t < 160) {
        const int mel = (t < 80) ? t : (t - 80);
        float s = 0.0f;
        if (t < 80) {
            #pragma unroll
            for (int i = 0; i < FRB; ++i) s += s_ss[i][mel];
        } else {
            #pragma unroll
            for (int i = 0; i < FRB; ++i) s += s_ss2[i][mel];
        }
        if (partMode)
            ws[WS_PART + (size_t)bid * 160 + t] = s;
        else
            atomicAdd(&ws[WS_ACC + b * 160 + t], s);
    }
}

// ---------------- Kernel 2: finalize stats (parallel over 8 rows) ----------------
__global__ __launch_bounds__(640) void stats_final_kernel(float* __restrict__ ws, int partMode)
{
    const int b = blockIdx.x;
    const int m = threadIdx.x;   // 0..79
    const int r = threadIdx.y;   // 0..7
    __shared__ float shs[8][NMEL], shs2[8][NMEL];
    float s = 0.0f, s2 = 0.0f;
    if (partMode) {
        for (int c = r; c < BPB; c += 8) {
            const float* base = ws + WS_PART + (size_t)(b * BPB + c) * 160;
            s += base[m];
            s2 += base[80 + m];
        }
    }
    shs[r][m] = s; shs2[r][m] = s2;
    __syncthreads();
    if (r == 0) {
        double ds = 0.0, ds2 = 0.0;
        if (partMode) {
            #pragma unroll
            for (int i = 0; i < 8; ++i) { ds += (double)shs[i][m]; ds2 += (double)shs2[i][m]; }
        } else {
            ds = (double)ws[WS_ACC + b * 160 + m];
            ds2 = (double)ws[WS_ACC + b * 160 + 80 + m];
        }
        double mean = ds / (double)F;
        double var = (ds2 - ds * ds / (double)F) / (double)(F - 1);
        ws[WS_STAT + b * 160 + m] = (float)mean;
        ws[WS_STAT + b * 160 + 80 + m] = (float)(1.0 / sqrt(var + 1e-7));
    }
}

// ---------------- Kernel 3: normalize (float4) + mask ----------------
__global__ __launch_bounds__(256) void norm_mask_kernel(
    float* __restrict__ out, const float* __restrict__ ws)
{
    const float* stat = ws + WS_STAT;
    const int total4 = (B * F * NMEL) / 4;
    const int stride = gridDim.x * blockDim.x;
    float4* out4 = (float4*)out;
    for (int e4 = blockIdx.x * blockDim.x + threadIdx.x; e4 < total4; e4 += stride) {
        int e = e4 * 4;
        int b = e / (F * NMEL);
        int m = e % NMEL;
        const float* sb = stat + b * 160;
        float4 v = out4[e4];
        v.x = (v.x - sb[m + 0]) * sb[80 + m + 0];
        v.y = (v.y - sb[m + 1]) * sb[80 + m + 1];
        v.z = (v.z - sb[m + 2]) * sb[80 + m + 2];
        v.w = (v.w - sb[m + 3]) * sb[80 + m + 3];
        out4[e4] = v;
    }
    const int nmask = B * (F / 2);
    float* mask = out + (size_t)B * F * NMEL;
    for (int e = blockIdx.x * blockDim.x + threadIdx.x; e < nmask; e += stride)
        mask[e] = 1.0f;
}

extern "C" void kernel_launch(void* const* d_in, const int* in_sizes, int n_in,
                              void* d_out, int out_size, void* d_ws, size_t ws_size,
                              hipStream_t stream) {
    const float* wav = (const float*)d_in[0];
    const float* fil = (const float*)d_in[1];
    const float* win = (const float*)d_in[2];
    float* out = (float*)d_out;
    float* ws = (float*)d_ws;

    const int partMode = (ws_size >= WS_NEED_PART) ? 1 : 0;

    setup_kernel<<<1, 256, 0, stream>>>(fil, ws);
    frame_logmel_kernel<<<NBLK, 512, 0, stream>>>(wav, win, ws, out, partMode);
    stats_final_kernel<<<B, dim3(NMEL, 8), 0, stream>>>(ws, partMode);
    norm_mask_kernel<<<2048, 256, 0, stream>>>(out, ws);
}

// Round 26
// 110.290 us; speedup vs baseline: 1.1596x; 1.0063x over previous
//
#include <hip/hip_runtime.h>
#include <math.h>

#define FRAME_LEN 400
#define NBINS 257
#define NMEL 80
#define MEL_FLOOR 1.192092955078125e-07f

constexpr int B = 16;
constexpr int T = 480000;
constexpr int F = 1 + (T - FRAME_LEN) / 160; // 2998
constexpr int FRB = 16;                       // frames per block (8 waves x 2 frames)
constexpr int BPB = (F + FRB - 1) / FRB;      // 188 blocks per batch
constexpr int NBLK = B * BPB;                 // 3008
constexpr int SPW = 292;                      // spec row width (max used idx 288)

// ws float offsets
#define WS_TW256C 0      // 256
#define WS_TW256S 256
#define WS_TW64C  512    // 32
#define WS_TW64S  544
#define WS_UNP4C  576    // float4[64]
#define WS_UNP4S  832
#define WS_K0     1088   // int[80]
#define WS_LEN    1168   // int[80]
#define WS_WGT    1280   // float[32*80] -> ends 3840
#define WS_ACC    3840   // float[16][2][80] atomic accumulators -> ends 6400
#define WS_STAT   6400   // float[16][2][80] mean/invstd -> ends 8960
#define WS_PART   9216   // float[3008][2][80] = 481280 -> ends 490496
constexpr size_t WS_NEED_PART = (size_t)(WS_PART + NBLK * 160) * 4;

__device__ __forceinline__ int brev6(int x) { return (int)(__brev((unsigned)x) >> 26); }
__device__ __forceinline__ int specIdx(int k) { return k + ((k >> 5) << 2); }

// ---------------- Kernel 0: build tables + zero atomic accumulators ----------------
__global__ __launch_bounds__(256) void setup_kernel(
    const float* __restrict__ fil, float* __restrict__ ws)
{
    const int t = threadIdx.x;
    float s, c;
    sincosf(-6.283185307179586f * (float)t / 256.0f, &s, &c);
    ws[WS_TW256C + t] = c; ws[WS_TW256S + t] = s;
    if (t < 32) {
        sincosf(-6.283185307179586f * (float)t / 64.0f, &s, &c);
        ws[WS_TW64C + t] = c; ws[WS_TW64S + t] = s;
    }
    if (t < 64) {
        int m = brev6(t);
        for (int j = 0; j < 4; ++j) {
            sincosf(-6.283185307179586f * (float)(4 * m + j) / 512.0f, &s, &c);
            ws[WS_UNP4C + 4 * t + j] = c;
            ws[WS_UNP4S + 4 * t + j] = s;
        }
    }
    for (int i = t; i < 2560; i += 256) ws[WS_ACC + i] = 0.0f;  // zero accumulators
    // sparse mel compaction
    __shared__ int sh_k0[3][NMEL], sh_k1[3][NMEL];
    __shared__ int sh_K0[NMEL], sh_LEN[NMEL];
    if (t < 240) {
        int m = t % NMEL, r = t / NMEL;
        int kb = r * 86, ke = (kb + 86 < NBINS) ? (kb + 86) : NBINS;
        int k0 = -1, k1 = -1;
        for (int k = kb; k < ke; ++k) {
            if (fil[k * NMEL + m] > 0.0f) { if (k0 < 0) k0 = k; k1 = k; }
        }
        sh_k0[r][m] = k0; sh_k1[r][m] = k1;
    }
    __syncthreads();
    if (t < NMEL) {
        int k0 = -1, k1 = -1;
        for (int r = 0; r < 3; ++r) {
            int a = sh_k0[r][t], b1 = sh_k1[r][t];
            if (a >= 0) { if (k0 < 0) k0 = a; k1 = b1; }
        }
        int len = (k0 < 0) ? 0 : (k1 - k0 + 1);
        if (len > 32) len = 32;
        if (k0 < 0) k0 = 0;
        ((int*)ws)[WS_K0 + t] = k0;
        ((int*)ws)[WS_LEN + t] = len;
        sh_K0[t] = k0; sh_LEN[t] = len;
    }
    __syncthreads();
    for (int idx = t; idx < 32 * NMEL; idx += 256) {
        int j = idx / NMEL, m = idx - j * NMEL;
        ws[WS_WGT + idx] = (j < sh_LEN[m]) ? fil[(sh_K0[m] + j) * NMEL + m] : 0.0f;
    }
}

// ---------------- Kernel 1: 2 frames per wave, 16 frames/block + fused stats (slim LDS) ----------------
__global__ __launch_bounds__(512, 6) void frame_logmel_kernel(
    const float* __restrict__ wav,
    const float* __restrict__ win,
    float* __restrict__ ws,
    float* __restrict__ mel_out,
    int partMode)
{
    __shared__ float s_t256c[256], s_t256s[256];
    __shared__ float s_t64c[32], s_t64s[32];
    __shared__ float4 s_upc[64], s_ups[64];
    __shared__ float s_wgt[32 * NMEL];
    __shared__ int s_k0[NMEL], s_len[NMEL];
    __shared__ float2 s_win2[200];
    __shared__ float s_spec[FRB][SPW];
    __shared__ float s_ss[FRB][NMEL];

    const int t = threadIdx.x;
    if (t < 256) {
        s_t256c[t] = ws[WS_TW256C + t];
        s_t256s[t] = ws[WS_TW256S + t];
    }
    if (t < 32) { s_t64c[t] = ws[WS_TW64C + t]; s_t64s[t] = ws[WS_TW64S + t]; }
    if (t < 64) {
        s_upc[t] = ((const float4*)(ws + WS_UNP4C))[t];
        s_ups[t] = ((const float4*)(ws + WS_UNP4S))[t];
    }
    for (int i = t; i < 32 * NMEL; i += 512) s_wgt[i] = ws[WS_WGT + i];
    if (t < NMEL) { s_k0[t] = ((const int*)ws)[WS_K0 + t]; s_len[t] = ((const int*)ws)[WS_LEN + t]; }
    if (t < 200) s_win2[t] = ((const float2*)win)[t];
    __syncthreads();  // tables ready

    const int l = t & 63, w = t >> 6;
    const int bid = blockIdx.x;
    const int b = bid / BPB, blk = bid - b * BPB;
    int fidx[2];
    bool live[2];
    const float2* src[2];
    #pragma unroll
    for (int ff = 0; ff < 2; ++ff) {
        fidx[ff] = blk * FRB + w * 2 + ff;
        live[ff] = (fidx[ff] < F);
        src[ff] = (const float2*)(wav + (size_t)b * T + (size_t)(live[ff] ? fidx[ff] : 0) * 160);
    }

    // load frames (complex-packed pairs), per-wave means (interleaved)
    float xr[2][4], xi[2][4];
    float sum[2] = {0.0f, 0.0f};
    #pragma unroll
    for (int ff = 0; ff < 2; ++ff) {
        #pragma unroll
        for (int j = 0; j < 4; ++j) {
            int p = 64 * j + l;
            float2 v = (live[ff] && p < 200) ? src[ff][p] : make_float2(0.0f, 0.0f);
            xr[ff][j] = v.x * 32768.0f;
            xi[ff][j] = v.y * 32768.0f;
            sum[ff] += xr[ff][j] + xi[ff][j];
        }
    }
    #pragma unroll
    for (int m = 32; m >= 1; m >>= 1) {
        sum[0] += __shfl_xor(sum[0], m);
        sum[1] += __shfl_xor(sum[1], m);
    }
    float mean[2] = {sum[0] * (1.0f / 400.0f), sum[1] * (1.0f / 400.0f)};

    // preemphasis + window
    float ur[2][4], ui[2][4];
    #pragma unroll
    for (int ff = 0; ff < 2; ++ff) {
        float zr[4], zi[4];
        float carry = 0.0f;
        #pragma unroll
        for (int j = 0; j < 4; ++j) {
            float y = xi[ff][j], x0 = xr[ff][j];
            float up = __shfl(y, (l + 63) & 63);
            float nc = __shfl(y, 63);
            if (l == 0) up = (j == 0) ? x0 : carry;
            carry = nc;
            int p = 64 * j + l;
            float2 w2 = (p < 200) ? s_win2[p] : make_float2(0.0f, 0.0f);
            zr[j] = (x0 - 0.97f * up - 0.03f * mean[ff]) * w2.x;
            zi[j] = (y - 0.97f * x0 - 0.03f * mean[ff]) * w2.y;
        }
        // in-lane radix-4 first stage
        float Ar = zr[0] + zr[2], Ai = zi[0] + zi[2];
        float Br = zr[0] - zr[2], Bi = zi[0] - zi[2];
        float Cr = zr[1] + zr[3], Ci = zi[1] + zi[3];
        float Dr = zr[1] - zr[3], Di = zi[1] - zi[3];
        ur[ff][0] = Ar + Cr; ui[ff][0] = Ai + Ci;
        ur[ff][1] = Br + Di; ui[ff][1] = Bi - Dr;
        ur[ff][2] = Ar - Cr; ui[ff][2] = Ai - Ci;
        ur[ff][3] = Br - Di; ui[ff][3] = Bi + Dr;
    }
    // W_256^{j*l} twiddles (both frames interleaved)
    {
        float w1r = s_t256c[l],     w1i = s_t256s[l];
        float w2r = s_t256c[2 * l], w2i = s_t256s[2 * l];
        float w3r = s_t256c[3 * l], w3i = s_t256s[3 * l];
        #pragma unroll
        for (int ff = 0; ff < 2; ++ff) {
            float tr;
            tr = ur[ff][1] * w1r - ui[ff][1] * w1i; ui[ff][1] = ur[ff][1] * w1i + ui[ff][1] * w1r; ur[ff][1] = tr;
            tr = ur[ff][2] * w2r - ui[ff][2] * w2i; ui[ff][2] = ur[ff][2] * w2i + ui[ff][2] * w2r; ur[ff][2] = tr;
            tr = ur[ff][3] * w3r - ui[ff][3] * w3i; ui[ff][3] = ur[ff][3] * w3i + ui[ff][3] * w3r; ur[ff][3] = tr;
        }
    }

    // 64-pt FFT across lanes, 2 frames x 4 values interleaved (8-way ILP)
    #pragma unroll
    for (int h = 32; h >= 1; h >>= 1) {
        int idx = (l & (h - 1)) * (32 / h);
        bool hi = (l & h) != 0;
        float wr = hi ? s_t64c[idx] : 1.0f;
        float wi = hi ? s_t64s[idx] : 0.0f;
        float sg = hi ? -1.0f : 1.0f;
        #pragma unroll
        for (int ff = 0; ff < 2; ++ff) {
            #pragma unroll
            for (int v = 0; v < 4; ++v) {
                float pr = __shfl_xor(ur[ff][v], h), pi = __shfl_xor(ui[ff][v], h);
                float sr = fmaf(sg, ur[ff][v], pr), si = fmaf(sg, ui[ff][v], pi);
                ur[ff][v] = sr * wr - si * wi;
                ui[ff][v] = sr * wi + si * wr;
            }
        }
    }

    // real-FFT unpack in-register, power spectrum (per frame)
    const int m = brev6(l);
    const int l0 = brev6((64 - m) & 63);
    const float4 wc = s_upc[l], wn = s_ups[l];
    #pragma unroll
    for (int ff = 0; ff < 2; ++ff) {
        float b1r = __shfl_xor(ur[ff][3], 63), b1i = __shfl_xor(ui[ff][3], 63);
        float b2r = __shfl_xor(ur[ff][2], 63), b2i = __shfl_xor(ui[ff][2], 63);
        float b3r = __shfl_xor(ur[ff][1], 63), b3i = __shfl_xor(ui[ff][1], 63);
        float b0r = __shfl(ur[ff][0], l0), b0i = __shfl(ui[ff][0], l0);
        float sp[4];
        #define UNP(J, ar, ai, br, bi, twr, twi)                        \
        {                                                               \
            float Er = 0.5f * (ar + br), Ei = 0.5f * (ai - bi);         \
            float Or = 0.5f * (ai + bi), Oi = 0.5f * (br - ar);         \
            float Xr = Er + twr * Or - twi * Oi;                        \
            float Xi = Ei + twr * Oi + twi * Or;                        \
            sp[J] = Xr * Xr + Xi * Xi;                                  \
        }
        UNP(0, ur[ff][0], ui[ff][0], b0r, b0i, wc.x, wn.x)
        UNP(1, ur[ff][1], ui[ff][1], b1r, b1i, wc.y, wn.y)
        UNP(2, ur[ff][2], ui[ff][2], b2r, b2i, wc.z, wn.z)
        UNP(3, ur[ff][3], ui[ff][3], b3r, b3i, wc.w, wn.w)
        #undef UNP
        ((float4*)s_spec[w * 2 + ff])[m + (m >> 3)] = make_float4(sp[0], sp[1], sp[2], sp[3]);
        if (l == 0) {
            float d = ur[ff][0] - ui[ff][0];  // X[256] = Re(Z0) - Im(Z0)
            s_spec[w * 2 + ff][specIdx(256)] = d * d;
        }
    }

    // sparse mel projection (wave-private spec; no barrier needed)
    const int q = l & 3;
    #pragma unroll
    for (int ff = 0; ff < 2; ++ff) {
        const int fr = w * 2 + ff;
        const size_t outbase = (size_t)(b * F + fidx[ff]) * NMEL;
        // narrow mels 0..63: one lane per mel
        float mv0;
        {
            int mel = l;
            int k0 = s_k0[mel], len = s_len[mel];
            float acc = 0.0f;
            for (int i = 0; i < len; ++i)
                acc = fmaf(s_spec[fr][specIdx(k0 + i)], s_wgt[i * NMEL + mel], acc);
            mv0 = __logf(fmaxf(acc, MEL_FLOOR));
            if (live[ff]) mel_out[outbase + l] = mv0;
        }
        // wide mels 64..79: 4 lanes per mel, shfl-combine
        float mv1 = 0.0f;
        {
            int mel = 64 + (l >> 2);
            int k0 = s_k0[mel], len = s_len[mel];
            float acc = 0.0f;
            for (int i = q; i < len; i += 4)
                acc = fmaf(s_spec[fr][specIdx(k0 + i)], s_wgt[i * NMEL + mel], acc);
            acc += __shfl_xor(acc, 1);
            acc += __shfl_xor(acc, 2);
            if (q == 0) {
                mv1 = __logf(fmaxf(acc, MEL_FLOOR));
                if (live[ff]) mel_out[outbase + mel] = mv1;
            }
        }
        // stats stage (values only; squares computed at reduction)
        s_ss[fr][l] = live[ff] ? mv0 : 0.0f;
        if (q == 0) s_ss[fr][64 + (l >> 2)] = live[ff] ? mv1 : 0.0f;
    }
    __syncthreads();
    if (t < 80) {
        float s = 0.0f, s2 = 0.0f;
        #pragma unroll
        for (int i = 0; i < FRB; ++i) {
            float v = s_ss[i][t];
            s += v;
            s2 += v * v;
        }
        if (partMode) {
            ws[WS_PART + (size_t)bid * 160 + t] = s;
            ws[WS_PART + (size_t)bid * 160 + 80 + t] = s2;
        } else {
            atomicAdd(&ws[WS_ACC + b * 160 + t], s);
            atomicAdd(&ws[WS_ACC + b * 160 + 80 + t], s2);
        }
    }
}

// ---------------- Kernel 2: finalize stats (parallel over 8 rows) ----------------
__global__ __launch_bounds__(640) void stats_final_kernel(float* __restrict__ ws, int partMode)
{
    const int b = blockIdx.x;
    const int m = threadIdx.x;   // 0..79
    const int r = threadIdx.y;   // 0..7
    __shared__ float shs[8][NMEL], shs2[8][NMEL];
    float s = 0.0f, s2 = 0.0f;
    if (partMode) {
        for (int c = r; c < BPB; c += 8) {
            const float* base = ws + WS_PART + (size_t)(b * BPB + c) * 160;
            s += base[m];
            s2 += base[80 + m];
        }
    }
    shs[r][m] = s; shs2[r][m] = s2;
    __syncthreads();
    if (r == 0) {
        double ds = 0.0, ds2 = 0.0;
        if (partMode) {
            #pragma unroll
            for (int i = 0; i < 8; ++i) { ds += (double)shs[i][m]; ds2 += (double)shs2[i][m]; }
        } else {
            ds = (double)ws[WS_ACC + b * 160 + m];
            ds2 = (double)ws[WS_ACC + b * 160 + 80 + m];
        }
        double mean = ds / (double)F;
        double var = (ds2 - ds * ds / (double)F) / (double)(F - 1);
        ws[WS_STAT + b * 160 + m] = (float)mean;
        ws[WS_STAT + b * 160 + 80 + m] = (float)(1.0 / sqrt(var + 1e-7));
    }
}

// ---------------- Kernel 3: normalize (float4) + mask ----------------
__global__ __launch_bounds__(256) void norm_mask_kernel(
    float* __restrict__ out, const float* __restrict__ ws)
{
    const float* stat = ws + WS_STAT;
    const int total4 = (B * F * NMEL) / 4;
    const int stride = gridDim.x * blockDim.x;
    float4* out4 = (float4*)out;
    for (int e4 = blockIdx.x * blockDim.x + threadIdx.x; e4 < total4; e4 += stride) {
        int e = e4 * 4;
        int b = e / (F * NMEL);
        int m = e % NMEL;
        const float* sb = stat + b * 160;
        float4 v = out4[e4];
        v.x = (v.x - sb[m + 0]) * sb[80 + m + 0];
        v.y = (v.y - sb[m + 1]) * sb[80 + m + 1];
        v.z = (v.z - sb[m + 2]) * sb[80 + m + 2];
        v.w = (v.w - sb[m + 3]) * sb[80 + m + 3];
        out4[e4] = v;
    }
    const int nmask = B * (F / 2);
    float* mask = out + (size_t)B * F * NMEL;
    for (int e = blockIdx.x * blockDim.x + threadIdx.x; e < nmask; e += stride)
        mask[e] = 1.0f;
}

extern "C" void kernel_launch(void* const* d_in, const int* in_sizes, int n_in,
                              void* d_out, int out_size, void* d_ws, size_t ws_size,
                              hipStream_t stream) {
    const float* wav = (const float*)d_in[0];
    const float* fil = (const float*)d_in[1];
    const float* win = (const float*)d_in[2];
    float* out = (float*)d_out;
    float* ws = (float*)d_ws;

    const int partMode = (ws_size >= WS_NEED_PART) ? 1 : 0;

    setup_kernel<<<1, 256, 0, stream>>>(fil, ws);
    frame_logmel_kernel<<<NBLK, 512, 0, stream>>>(wav, win, ws, out, partMode);
    stats_final_kernel<<<B, dim3(NMEL, 8), 0, stream>>>(ws, partMode);
    norm_mask_kernel<<<2048, 256, 0, stream>>>(out, ws);
}

// Round 27
// 103.621 us; speedup vs baseline: 1.2343x; 1.0644x over previous
//
#include <hip/hip_runtime.h>
#include <math.h>

#define FRAME_LEN 400
#define NBINS 257
#define NMEL 80
#define MEL_FLOOR 1.192092955078125e-07f

constexpr int B = 16;
constexpr int T = 480000;
constexpr int F = 1 + (T - FRAME_LEN) / 160; // 2998
constexpr int FRB = 16;                       // frames per block (8 waves x 2 frames)
constexpr int BPB = (F + FRB - 1) / FRB;      // 188 blocks per batch
constexpr int NBLK = B * BPB;                 // 3008
constexpr int SPW = 292;                      // spec row width (max used idx 288)

// ws float offsets
#define WS_TW256C 0      // 256
#define WS_TW256S 256
#define WS_TW64C  512    // 32
#define WS_TW64S  544
#define WS_UNP4C  576    // float4[64]
#define WS_UNP4S  832
#define WS_K0     1088   // int[80]
#define WS_LEN    1168   // int[80]
#define WS_WGT    1280   // float[32*80] -> ends 3840
#define WS_ACC    3840   // float[16][2][80] atomic accumulators -> ends 6400
#define WS_STAT   6400   // float[16][2][80] mean/invstd -> ends 8960
#define WS_PART   9216   // float[3008][2][80] = 481280 -> ends 490496
constexpr size_t WS_NEED_PART = (size_t)(WS_PART + NBLK * 160) * 4;

__device__ __forceinline__ int brev6(int x) { return (int)(__brev((unsigned)x) >> 26); }
__device__ __forceinline__ int specIdx(int k) { return k + ((k >> 5) << 2); }

// quad_perm DPP lane exchange (VALU pipe; bit-exact xor-1 / xor-2 within quads)
template<int CTRL>
__device__ __forceinline__ float dppf(float x) {
    union { float f; int i; } u, r;
    u.f = x;
    r.i = __builtin_amdgcn_update_dpp(0, u.i, CTRL, 0xF, 0xF, true);
    return r.f;
}
#define DPP_XOR1 0xB1   // quad_perm [1,0,3,2]
#define DPP_XOR2 0x4E   // quad_perm [2,3,0,1]

// ---------------- Kernel 0: build tables + zero atomic accumulators ----------------
__global__ __launch_bounds__(256) void setup_kernel(
    const float* __restrict__ fil, float* __restrict__ ws)
{
    const int t = threadIdx.x;
    float s, c;
    sincosf(-6.283185307179586f * (float)t / 256.0f, &s, &c);
    ws[WS_TW256C + t] = c; ws[WS_TW256S + t] = s;
    if (t < 32) {
        sincosf(-6.283185307179586f * (float)t / 64.0f, &s, &c);
        ws[WS_TW64C + t] = c; ws[WS_TW64S + t] = s;
    }
    if (t < 64) {
        int m = brev6(t);
        for (int j = 0; j < 4; ++j) {
            sincosf(-6.283185307179586f * (float)(4 * m + j) / 512.0f, &s, &c);
            ws[WS_UNP4C + 4 * t + j] = c;
            ws[WS_UNP4S + 4 * t + j] = s;
        }
    }
    for (int i = t; i < 2560; i += 256) ws[WS_ACC + i] = 0.0f;  // zero accumulators
    // sparse mel compaction
    __shared__ int sh_k0[3][NMEL], sh_k1[3][NMEL];
    __shared__ int sh_K0[NMEL], sh_LEN[NMEL];
    if (t < 240) {
        int m = t % NMEL, r = t / NMEL;
        int kb = r * 86, ke = (kb + 86 < NBINS) ? (kb + 86) : NBINS;
        int k0 = -1, k1 = -1;
        for (int k = kb; k < ke; ++k) {
            if (fil[k * NMEL + m] > 0.0f) { if (k0 < 0) k0 = k; k1 = k; }
        }
        sh_k0[r][m] = k0; sh_k1[r][m] = k1;
    }
    __syncthreads();
    if (t < NMEL) {
        int k0 = -1, k1 = -1;
        for (int r = 0; r < 3; ++r) {
            int a = sh_k0[r][t], b1 = sh_k1[r][t];
            if (a >= 0) { if (k0 < 0) k0 = a; k1 = b1; }
        }
        int len = (k0 < 0) ? 0 : (k1 - k0 + 1);
        if (len > 32) len = 32;
        if (k0 < 0) k0 = 0;
        ((int*)ws)[WS_K0 + t] = k0;
        ((int*)ws)[WS_LEN + t] = len;
        sh_K0[t] = k0; sh_LEN[t] = len;
    }
    __syncthreads();
    for (int idx = t; idx < 32 * NMEL; idx += 256) {
        int j = idx / NMEL, m = idx - j * NMEL;
        ws[WS_WGT + idx] = (j < sh_LEN[m]) ? fil[(sh_K0[m] + j) * NMEL + m] : 0.0f;
    }
}

// ---------------- Kernel 1: 2 frames/wave, 16 frames/block, DPP for xor1/xor2 ----------------
__global__ __launch_bounds__(512, 6) void frame_logmel_kernel(
    const float* __restrict__ wav,
    const float* __restrict__ win,
    float* __restrict__ ws,
    float* __restrict__ mel_out,
    int partMode)
{
    __shared__ float s_t256c[256], s_t256s[256];
    __shared__ float s_t64c[32], s_t64s[32];
    __shared__ float4 s_upc[64], s_ups[64];
    __shared__ float s_wgt[32 * NMEL];
    __shared__ int s_k0[NMEL], s_len[NMEL];
    __shared__ float2 s_win2[200];
    __shared__ float s_spec[FRB][SPW];
    __shared__ float s_ss[FRB][NMEL];

    const int t = threadIdx.x;
    if (t < 256) {
        s_t256c[t] = ws[WS_TW256C + t];
        s_t256s[t] = ws[WS_TW256S + t];
    }
    if (t < 32) { s_t64c[t] = ws[WS_TW64C + t]; s_t64s[t] = ws[WS_TW64S + t]; }
    if (t < 64) {
        s_upc[t] = ((const float4*)(ws + WS_UNP4C))[t];
        s_ups[t] = ((const float4*)(ws + WS_UNP4S))[t];
    }
    for (int i = t; i < 32 * NMEL; i += 512) s_wgt[i] = ws[WS_WGT + i];
    if (t < NMEL) { s_k0[t] = ((const int*)ws)[WS_K0 + t]; s_len[t] = ((const int*)ws)[WS_LEN + t]; }
    if (t < 200) s_win2[t] = ((const float2*)win)[t];
    __syncthreads();  // tables ready

    const int l = t & 63, w = t >> 6;
    const int bid = blockIdx.x;
    const int b = bid / BPB, blk = bid - b * BPB;
    int fidx[2];
    bool live[2];
    const float2* src[2];
    #pragma unroll
    for (int ff = 0; ff < 2; ++ff) {
        fidx[ff] = blk * FRB + w * 2 + ff;
        live[ff] = (fidx[ff] < F);
        src[ff] = (const float2*)(wav + (size_t)b * T + (size_t)(live[ff] ? fidx[ff] : 0) * 160);
    }

    // load frames (complex-packed pairs), per-wave means (interleaved)
    float xr[2][4], xi[2][4];
    float sum[2] = {0.0f, 0.0f};
    #pragma unroll
    for (int ff = 0; ff < 2; ++ff) {
        #pragma unroll
        for (int j = 0; j < 4; ++j) {
            int p = 64 * j + l;
            float2 v = (live[ff] && p < 200) ? src[ff][p] : make_float2(0.0f, 0.0f);
            xr[ff][j] = v.x * 32768.0f;
            xi[ff][j] = v.y * 32768.0f;
            sum[ff] += xr[ff][j] + xi[ff][j];
        }
    }
    #pragma unroll
    for (int m = 32; m >= 4; m >>= 1) {
        sum[0] += __shfl_xor(sum[0], m);
        sum[1] += __shfl_xor(sum[1], m);
    }
    sum[0] += dppf<DPP_XOR2>(sum[0]); sum[1] += dppf<DPP_XOR2>(sum[1]);
    sum[0] += dppf<DPP_XOR1>(sum[0]); sum[1] += dppf<DPP_XOR1>(sum[1]);
    float mean[2] = {sum[0] * (1.0f / 400.0f), sum[1] * (1.0f / 400.0f)};

    // preemphasis + window
    float ur[2][4], ui[2][4];
    #pragma unroll
    for (int ff = 0; ff < 2; ++ff) {
        float zr[4], zi[4];
        float carry = 0.0f;
        #pragma unroll
        for (int j = 0; j < 4; ++j) {
            float y = xi[ff][j], x0 = xr[ff][j];
            float up = __shfl(y, (l + 63) & 63);
            float nc = __shfl(y, 63);
            if (l == 0) up = (j == 0) ? x0 : carry;
            carry = nc;
            int p = 64 * j + l;
            float2 w2 = (p < 200) ? s_win2[p] : make_float2(0.0f, 0.0f);
            zr[j] = (x0 - 0.97f * up - 0.03f * mean[ff]) * w2.x;
            zi[j] = (y - 0.97f * x0 - 0.03f * mean[ff]) * w2.y;
        }
        // in-lane radix-4 first stage
        float Ar = zr[0] + zr[2], Ai = zi[0] + zi[2];
        float Br = zr[0] - zr[2], Bi = zi[0] - zi[2];
        float Cr = zr[1] + zr[3], Ci = zi[1] + zi[3];
        float Dr = zr[1] - zr[3], Di = zi[1] - zi[3];
        ur[ff][0] = Ar + Cr; ui[ff][0] = Ai + Ci;
        ur[ff][1] = Br + Di; ui[ff][1] = Bi - Dr;
        ur[ff][2] = Ar - Cr; ui[ff][2] = Ai - Ci;
        ur[ff][3] = Br - Di; ui[ff][3] = Bi + Dr;
    }
    // W_256^{j*l} twiddles (both frames interleaved)
    {
        float w1r = s_t256c[l],     w1i = s_t256s[l];
        float w2r = s_t256c[2 * l], w2i = s_t256s[2 * l];
        float w3r = s_t256c[3 * l], w3i = s_t256s[3 * l];
        #pragma unroll
        for (int ff = 0; ff < 2; ++ff) {
            float tr;
            tr = ur[ff][1] * w1r - ui[ff][1] * w1i; ui[ff][1] = ur[ff][1] * w1i + ui[ff][1] * w1r; ur[ff][1] = tr;
            tr = ur[ff][2] * w2r - ui[ff][2] * w2i; ui[ff][2] = ur[ff][2] * w2i + ui[ff][2] * w2r; ur[ff][2] = tr;
            tr = ur[ff][3] * w3r - ui[ff][3] * w3i; ui[ff][3] = ur[ff][3] * w3i + ui[ff][3] * w3r; ur[ff][3] = tr;
        }
    }

    // 64-pt FFT across lanes; h>=4 via bpermute, h=2/1 via DPP quad_perm (VALU)
    #pragma unroll
    for (int h = 32; h >= 1; h >>= 1) {
        int idx = (l & (h - 1)) * (32 / h);
        bool hi = (l & h) != 0;
        float wr = hi ? s_t64c[idx] : 1.0f;
        float wi = hi ? s_t64s[idx] : 0.0f;
        float sg = hi ? -1.0f : 1.0f;
        #pragma unroll
        for (int ff = 0; ff < 2; ++ff) {
            #pragma unroll
            for (int v = 0; v < 4; ++v) {
                float pr, pi;
                if (h == 2) {
                    pr = dppf<DPP_XOR2>(ur[ff][v]); pi = dppf<DPP_XOR2>(ui[ff][v]);
                } else if (h == 1) {
                    pr = dppf<DPP_XOR1>(ur[ff][v]); pi = dppf<DPP_XOR1>(ui[ff][v]);
                } else {
                    pr = __shfl_xor(ur[ff][v], h); pi = __shfl_xor(ui[ff][v], h);
                }
                float sr = fmaf(sg, ur[ff][v], pr), si = fmaf(sg, ui[ff][v], pi);
                ur[ff][v] = sr * wr - si * wi;
                ui[ff][v] = sr * wi + si * wr;
            }
        }
    }

    // real-FFT unpack in-register, power spectrum (per frame)
    const int m = brev6(l);
    const int l0 = brev6((64 - m) & 63);
    const float4 wc = s_upc[l], wn = s_ups[l];
    #pragma unroll
    for (int ff = 0; ff < 2; ++ff) {
        float b1r = __shfl_xor(ur[ff][3], 63), b1i = __shfl_xor(ui[ff][3], 63);
        float b2r = __shfl_xor(ur[ff][2], 63), b2i = __shfl_xor(ui[ff][2], 63);
        float b3r = __shfl_xor(ur[ff][1], 63), b3i = __shfl_xor(ui[ff][1], 63);
        float b0r = __shfl(ur[ff][0], l0), b0i = __shfl(ui[ff][0], l0);
        float sp[4];
        #define UNP(J, ar, ai, br, bi, twr, twi)                        \
        {                                                               \
            float Er = 0.5f * (ar + br), Ei = 0.5f * (ai - bi);         \
            float Or = 0.5f * (ai + bi), Oi = 0.5f * (br - ar);         \
            float Xr = Er + twr * Or - twi * Oi;                        \
            float Xi = Ei + twr * Oi + twi * Or;                        \
            sp[J] = Xr * Xr + Xi * Xi;                                  \
        }
        UNP(0, ur[ff][0], ui[ff][0], b0r, b0i, wc.x, wn.x)
        UNP(1, ur[ff][1], ui[ff][1], b1r, b1i, wc.y, wn.y)
        UNP(2, ur[ff][2], ui[ff][2], b2r, b2i, wc.z, wn.z)
        UNP(3, ur[ff][3], ui[ff][3], b3r, b3i, wc.w, wn.w)
        #undef UNP
        ((float4*)s_spec[w * 2 + ff])[m + (m >> 3)] = make_float4(sp[0], sp[1], sp[2], sp[3]);
        if (l == 0) {
            float d = ur[ff][0] - ui[ff][0];  // X[256] = Re(Z0) - Im(Z0)
            s_spec[w * 2 + ff][specIdx(256)] = d * d;
        }
    }

    // sparse mel projection (wave-private spec; no barrier needed)
    const int q = l & 3;
    #pragma unroll
    for (int ff = 0; ff < 2; ++ff) {
        const int fr = w * 2 + ff;
        const size_t outbase = (size_t)(b * F + fidx[ff]) * NMEL;
        // narrow mels 0..63: one lane per mel
        float mv0;
        {
            int mel = l;
            int k0 = s_k0[mel], len = s_len[mel];
            float acc = 0.0f;
            for (int i = 0; i < len; ++i)
                acc = fmaf(s_spec[fr][specIdx(k0 + i)], s_wgt[i * NMEL + mel], acc);
            mv0 = __logf(fmaxf(acc, MEL_FLOOR));
            if (live[ff]) mel_out[outbase + l] = mv0;
        }
        // wide mels 64..79: 4 lanes per mel, DPP-combine
        float mv1 = 0.0f;
        {
            int mel = 64 + (l >> 2);
            int k0 = s_k0[mel], len = s_len[mel];
            float acc = 0.0f;
            for (int i = q; i < len; i += 4)
                acc = fmaf(s_spec[fr][specIdx(k0 + i)], s_wgt[i * NMEL + mel], acc);
            acc += dppf<DPP_XOR1>(acc);
            acc += dppf<DPP_XOR2>(acc);
            if (q == 0) {
                mv1 = __logf(fmaxf(acc, MEL_FLOOR));
                if (live[ff]) mel_out[outbase + mel] = mv1;
            }
        }
        // stats stage (values only; squares computed at reduction)
        s_ss[fr][l] = live[ff] ? mv0 : 0.0f;
        if (q == 0) s_ss[fr][64 + (l >> 2)] = live[ff] ? mv1 : 0.0f;
    }
    __syncthreads();
    if (t < 80) {
        float s = 0.0f, s2 = 0.0f;
        #pragma unroll
        for (int i = 0; i < FRB; ++i) {
            float v = s_ss[i][t];
            s += v;
            s2 += v * v;
        }
        if (partMode) {
            ws[WS_PART + (size_t)bid * 160 + t] = s;
            ws[WS_PART + (size_t)bid * 160 + 80 + t] = s2;
        } else {
            atomicAdd(&ws[WS_ACC + b * 160 + t], s);
            atomicAdd(&ws[WS_ACC + b * 160 + 80 + t], s2);
        }
    }
}

// ---------------- Kernel 2: finalize stats (parallel over 8 rows) ----------------
__global__ __launch_bounds__(640) void stats_final_kernel(float* __restrict__ ws, int partMode)
{
    const int b = blockIdx.x;
    const int m = threadIdx.x;   // 0..79
    const int r = threadIdx.y;   // 0..7
    __shared__ float shs[8][NMEL], shs2[8][NMEL];
    float s = 0.0f, s2 = 0.0f;
    if (partMode) {
        for (int c = r; c < BPB; c += 8) {
            const float* base = ws + WS_PART + (size_t)(b * BPB + c) * 160;
            s += base[m];
            s2 += base[80 + m];
        }
    }
    shs[r][m] = s; shs2[r][m] = s2;
    __syncthreads();
    if (r == 0) {
        double ds = 0.0, ds2 = 0.0;
        if (partMode) {
            #pragma unroll
            for (int i = 0; i < 8; ++i) { ds += (double)shs[i][m]; ds2 += (double)shs2[i][m]; }
        } else {
            ds = (double)ws[WS_ACC + b * 160 + m];
            ds2 = (double)ws[WS_ACC + b * 160 + 80 + m];
        }
        double mean = ds / (double)F;
        double var = (ds2 - ds * ds / (double)F) / (double)(F - 1);
        ws[WS_STAT + b * 160 + m] = (float)mean;
        ws[WS_STAT + b * 160 + 80 + m] = (float)(1.0 / sqrt(var + 1e-7));
    }
}

// ---------------- Kernel 3: normalize (float4) + mask ----------------
__global__ __launch_bounds__(256) void norm_mask_kernel(
    float* __restrict__ out, const float* __restrict__ ws)
{
    const float* stat = ws + WS_STAT;
    const int total4 = (B * F * NMEL) / 4;
    const int stride = gridDim.x * blockDim.x;
    float4* out4 = (float4*)out;
    for (int e4 = blockIdx.x * blockDim.x + threadIdx.x; e4 < total4; e4 += stride) {
        int e = e4 * 4;
        int b = e / (F * NMEL);
        int m = e % NMEL;
        const float* sb = stat + b * 160;
        float4 v = out4[e4];
        v.x = (v.x - sb[m + 0]) * sb[80 + m + 0];
        v.y = (v.y - sb[m + 1]) * sb[80 + m + 1];
        v.z = (v.z - sb[m + 2]) * sb[80 + m + 2];
        v.w = (v.w - sb[m + 3]) * sb[80 + m + 3];
        out4[e4] = v;
    }
    const int nmask = B * (F / 2);
    float* mask = out + (size_t)B * F * NMEL;
    for (int e = blockIdx.x * blockDim.x + threadIdx.x; e < nmask; e += stride)
        mask[e] = 1.0f;
}

extern "C" void kernel_launch(void* const* d_in, const int* in_sizes, int n_in,
                              void* d_out, int out_size, void* d_ws, size_t ws_size,
                              hipStream_t stream) {
    const float* wav = (const float*)d_in[0];
    const float* fil = (const float*)d_in[1];
    const float* win = (const float*)d_in[2];
    float* out = (float*)d_out;
    float* ws = (float*)d_ws;

    const int partMode = (ws_size >= WS_NEED_PART) ? 1 : 0;

    setup_kernel<<<1, 256, 0, stream>>>(fil, ws);
    frame_logmel_kernel<<<NBLK, 512, 0, stream>>>(wav, win, ws, out, partMode);
    stats_final_kernel<<<B, dim3(NMEL, 8), 0, stream>>>(ws, partMode);
    norm_mask_kernel<<<2048, 256, 0, stream>>>(out, ws);
}

// Round 28
// 102.408 us; speedup vs baseline: 1.2489x; 1.0118x over previous
//
#include <hip/hip_runtime.h>
#include <math.h>

#define FRAME_LEN 400
#define NBINS 257
#define NMEL 80
#define MEL_FLOOR 1.192092955078125e-07f

constexpr int B = 16;
constexpr int T = 480000;
constexpr int F = 1 + (T - FRAME_LEN) / 160; // 2998
constexpr int FRB = 16;                       // frames per block (8 waves x 2 frames)
constexpr int BPB = (F + FRB - 1) / FRB;      // 188 blocks per batch
constexpr int NBLK = B * BPB;                 // 3008
constexpr int SPW = 292;                      // spec row width (max used idx 288)

// ws float offsets
#define WS_TW256C 0      // 256
#define WS_TW256S 256
#define WS_TW64C  512    // 32
#define WS_TW64S  544
#define WS_UNP4C  576    // float4[64]
#define WS_UNP4S  832
#define WS_K0     1088   // int[80]
#define WS_LEN    1168   // int[80]
#define WS_WGT    1280   // float[32*80] -> ends 3840
#define WS_ACC    3840   // float[16][2][80] atomic accumulators -> ends 6400
#define WS_STAT   6400   // float[16][2][80] mean/invstd -> ends 8960
#define WS_PART   9216   // float[3008][2][80] = 481280 -> ends 490496
constexpr size_t WS_NEED_PART = (size_t)(WS_PART + NBLK * 160) * 4;

__device__ __forceinline__ int brev6(int x) { return (int)(__brev((unsigned)x) >> 26); }
__device__ __forceinline__ int specIdx(int k) { return k + ((k >> 5) << 2); }

// quad_perm DPP lane exchange (VALU pipe; bit-exact xor-1 / xor-2 within quads)
template<int CTRL>
__device__ __forceinline__ float dppf(float x) {
    union { float f; int i; } u, r;
    u.f = x;
    r.i = __builtin_amdgcn_update_dpp(0, u.i, CTRL, 0xF, 0xF, true);
    return r.f;
}
#define DPP_XOR1 0xB1   // quad_perm [1,0,3,2]
#define DPP_XOR2 0x4E   // quad_perm [2,3,0,1]

// xor-16 / xor-32 lane exchange via gfx950 permlane swaps (VALU pipe).
// The swap returns {new_a, new_b} which at each lane contain {self, partner}
// in some order; r[0]^r[1]^self == partner bit-exactly, convention-proof.
typedef int i32x2 __attribute__((ext_vector_type(2)));
__device__ __forceinline__ float swap16f(float x) {
    union { float f; int i; } u; u.f = x;
    i32x2 r = __builtin_amdgcn_permlane16_swap(u.i, u.i, false, false);
    union { int i; float f; } o;
    o.i = r[0] ^ r[1] ^ u.i;
    return o.f;
}
__device__ __forceinline__ float swap32f(float x) {
    union { float f; int i; } u; u.f = x;
    i32x2 r = __builtin_amdgcn_permlane32_swap(u.i, u.i, false, false);
    union { int i; float f; } o;
    o.i = r[0] ^ r[1] ^ u.i;
    return o.f;
}

// ---------------- Kernel 0: build tables + zero atomic accumulators ----------------
__global__ __launch_bounds__(256) void setup_kernel(
    const float* __restrict__ fil, float* __restrict__ ws)
{
    const int t = threadIdx.x;
    float s, c;
    sincosf(-6.283185307179586f * (float)t / 256.0f, &s, &c);
    ws[WS_TW256C + t] = c; ws[WS_TW256S + t] = s;
    if (t < 32) {
        sincosf(-6.283185307179586f * (float)t / 64.0f, &s, &c);
        ws[WS_TW64C + t] = c; ws[WS_TW64S + t] = s;
    }
    if (t < 64) {
        int m = brev6(t);
        for (int j = 0; j < 4; ++j) {
            sincosf(-6.283185307179586f * (float)(4 * m + j) / 512.0f, &s, &c);
            ws[WS_UNP4C + 4 * t + j] = c;
            ws[WS_UNP4S + 4 * t + j] = s;
        }
    }
    for (int i = t; i < 2560; i += 256) ws[WS_ACC + i] = 0.0f;  // zero accumulators
    // sparse mel compaction
    __shared__ int sh_k0[3][NMEL], sh_k1[3][NMEL];
    __shared__ int sh_K0[NMEL], sh_LEN[NMEL];
    if (t < 240) {
        int m = t % NMEL, r = t / NMEL;
        int kb = r * 86, ke = (kb + 86 < NBINS) ? (kb + 86) : NBINS;
        int k0 = -1, k1 = -1;
        for (int k = kb; k < ke; ++k) {
            if (fil[k * NMEL + m] > 0.0f) { if (k0 < 0) k0 = k; k1 = k; }
        }
        sh_k0[r][m] = k0; sh_k1[r][m] = k1;
    }
    __syncthreads();
    if (t < NMEL) {
        int k0 = -1, k1 = -1;
        for (int r = 0; r < 3; ++r) {
            int a = sh_k0[r][t], b1 = sh_k1[r][t];
            if (a >= 0) { if (k0 < 0) k0 = a; k1 = b1; }
        }
        int len = (k0 < 0) ? 0 : (k1 - k0 + 1);
        if (len > 32) len = 32;
        if (k0 < 0) k0 = 0;
        ((int*)ws)[WS_K0 + t] = k0;
        ((int*)ws)[WS_LEN + t] = len;
        sh_K0[t] = k0; sh_LEN[t] = len;
    }
    __syncthreads();
    for (int idx = t; idx < 32 * NMEL; idx += 256) {
        int j = idx / NMEL, m = idx - j * NMEL;
        ws[WS_WGT + idx] = (j < sh_LEN[m]) ? fil[(sh_K0[m] + j) * NMEL + m] : 0.0f;
    }
}

// ---------------- Kernel 1: 2 frames/wave, 16 frames/block, DPP+permlane cross-lane ----------------
__global__ __launch_bounds__(512, 6) void frame_logmel_kernel(
    const float* __restrict__ wav,
    const float* __restrict__ win,
    float* __restrict__ ws,
    float* __restrict__ mel_out,
    int partMode)
{
    __shared__ float s_t256c[256], s_t256s[256];
    __shared__ float s_t64c[32], s_t64s[32];
    __shared__ float4 s_upc[64], s_ups[64];
    __shared__ float s_wgt[32 * NMEL];
    __shared__ int s_k0[NMEL], s_len[NMEL];
    __shared__ float2 s_win2[200];
    __shared__ float s_spec[FRB][SPW];
    __shared__ float s_ss[FRB][NMEL];

    const int t = threadIdx.x;
    if (t < 256) {
        s_t256c[t] = ws[WS_TW256C + t];
        s_t256s[t] = ws[WS_TW256S + t];
    }
    if (t < 32) { s_t64c[t] = ws[WS_TW64C + t]; s_t64s[t] = ws[WS_TW64S + t]; }
    if (t < 64) {
        s_upc[t] = ((const float4*)(ws + WS_UNP4C))[t];
        s_ups[t] = ((const float4*)(ws + WS_UNP4S))[t];
    }
    for (int i = t; i < 32 * NMEL; i += 512) s_wgt[i] = ws[WS_WGT + i];
    if (t < NMEL) { s_k0[t] = ((const int*)ws)[WS_K0 + t]; s_len[t] = ((const int*)ws)[WS_LEN + t]; }
    if (t < 200) s_win2[t] = ((const float2*)win)[t];
    __syncthreads();  // tables ready

    const int l = t & 63, w = t >> 6;
    const int bid = blockIdx.x;
    const int b = bid / BPB, blk = bid - b * BPB;
    int fidx[2];
    bool live[2];
    const float2* src[2];
    #pragma unroll
    for (int ff = 0; ff < 2; ++ff) {
        fidx[ff] = blk * FRB + w * 2 + ff;
        live[ff] = (fidx[ff] < F);
        src[ff] = (const float2*)(wav + (size_t)b * T + (size_t)(live[ff] ? fidx[ff] : 0) * 160);
    }

    // load frames (complex-packed pairs), per-wave means (interleaved)
    float xr[2][4], xi[2][4];
    float sum[2] = {0.0f, 0.0f};
    #pragma unroll
    for (int ff = 0; ff < 2; ++ff) {
        #pragma unroll
        for (int j = 0; j < 4; ++j) {
            int p = 64 * j + l;
            float2 v = (live[ff] && p < 200) ? src[ff][p] : make_float2(0.0f, 0.0f);
            xr[ff][j] = v.x * 32768.0f;
            xi[ff][j] = v.y * 32768.0f;
            sum[ff] += xr[ff][j] + xi[ff][j];
        }
    }
    sum[0] += swap32f(sum[0]);           sum[1] += swap32f(sum[1]);
    sum[0] += swap16f(sum[0]);           sum[1] += swap16f(sum[1]);
    sum[0] += __shfl_xor(sum[0], 8);     sum[1] += __shfl_xor(sum[1], 8);
    sum[0] += __shfl_xor(sum[0], 4);     sum[1] += __shfl_xor(sum[1], 4);
    sum[0] += dppf<DPP_XOR2>(sum[0]);    sum[1] += dppf<DPP_XOR2>(sum[1]);
    sum[0] += dppf<DPP_XOR1>(sum[0]);    sum[1] += dppf<DPP_XOR1>(sum[1]);
    float mean[2] = {sum[0] * (1.0f / 400.0f), sum[1] * (1.0f / 400.0f)};

    // preemphasis + window
    float ur[2][4], ui[2][4];
    #pragma unroll
    for (int ff = 0; ff < 2; ++ff) {
        float zr[4], zi[4];
        float carry = 0.0f;
        #pragma unroll
        for (int j = 0; j < 4; ++j) {
            float y = xi[ff][j], x0 = xr[ff][j];
            float up = __shfl(y, (l + 63) & 63);
            float nc = __shfl(y, 63);
            if (l == 0) up = (j == 0) ? x0 : carry;
            carry = nc;
            int p = 64 * j + l;
            float2 w2 = (p < 200) ? s_win2[p] : make_float2(0.0f, 0.0f);
            zr[j] = (x0 - 0.97f * up - 0.03f * mean[ff]) * w2.x;
            zi[j] = (y - 0.97f * x0 - 0.03f * mean[ff]) * w2.y;
        }
        // in-lane radix-4 first stage
        float Ar = zr[0] + zr[2], Ai = zi[0] + zi[2];
        float Br = zr[0] - zr[2], Bi = zi[0] - zi[2];
        float Cr = zr[1] + zr[3], Ci = zi[1] + zi[3];
        float Dr = zr[1] - zr[3], Di = zi[1] - zi[3];
        ur[ff][0] = Ar + Cr; ui[ff][0] = Ai + Ci;
        ur[ff][1] = Br + Di; ui[ff][1] = Bi - Dr;
        ur[ff][2] = Ar - Cr; ui[ff][2] = Ai - Ci;
        ur[ff][3] = Br - Di; ui[ff][3] = Bi + Dr;
    }
    // W_256^{j*l} twiddles (both frames interleaved)
    {
        float w1r = s_t256c[l],     w1i = s_t256s[l];
        float w2r = s_t256c[2 * l], w2i = s_t256s[2 * l];
        float w3r = s_t256c[3 * l], w3i = s_t256s[3 * l];
        #pragma unroll
        for (int ff = 0; ff < 2; ++ff) {
            float tr;
            tr = ur[ff][1] * w1r - ui[ff][1] * w1i; ui[ff][1] = ur[ff][1] * w1i + ui[ff][1] * w1r; ur[ff][1] = tr;
            tr = ur[ff][2] * w2r - ui[ff][2] * w2i; ui[ff][2] = ur[ff][2] * w2i + ui[ff][2] * w2r; ur[ff][2] = tr;
            tr = ur[ff][3] * w3r - ui[ff][3] * w3i; ui[ff][3] = ur[ff][3] * w3i + ui[ff][3] * w3r; ur[ff][3] = tr;
        }
    }

    // 64-pt FFT across lanes; h=32/16 via permlane swap, h=8/4 via bpermute, h=2/1 via DPP
    #pragma unroll
    for (int h = 32; h >= 1; h >>= 1) {
        int idx = (l & (h - 1)) * (32 / h);
        bool hi = (l & h) != 0;
        float wr = hi ? s_t64c[idx] : 1.0f;
        float wi = hi ? s_t64s[idx] : 0.0f;
        float sg = hi ? -1.0f : 1.0f;
        #pragma unroll
        for (int ff = 0; ff < 2; ++ff) {
            #pragma unroll
            for (int v = 0; v < 4; ++v) {
                float pr, pi;
                if (h == 32) {
                    pr = swap32f(ur[ff][v]); pi = swap32f(ui[ff][v]);
                } else if (h == 16) {
                    pr = swap16f(ur[ff][v]); pi = swap16f(ui[ff][v]);
                } else if (h == 2) {
                    pr = dppf<DPP_XOR2>(ur[ff][v]); pi = dppf<DPP_XOR2>(ui[ff][v]);
                } else if (h == 1) {
                    pr = dppf<DPP_XOR1>(ur[ff][v]); pi = dppf<DPP_XOR1>(ui[ff][v]);
                } else {
                    pr = __shfl_xor(ur[ff][v], h); pi = __shfl_xor(ui[ff][v], h);
                }
                float sr = fmaf(sg, ur[ff][v], pr), si = fmaf(sg, ui[ff][v], pi);
                ur[ff][v] = sr * wr - si * wi;
                ui[ff][v] = sr * wi + si * wr;
            }
        }
    }

    // real-FFT unpack in-register, power spectrum (per frame)
    const int m = brev6(l);
    const int l0 = brev6((64 - m) & 63);
    const float4 wc = s_upc[l], wn = s_ups[l];
    #pragma unroll
    for (int ff = 0; ff < 2; ++ff) {
        float b1r = __shfl_xor(ur[ff][3], 63), b1i = __shfl_xor(ui[ff][3], 63);
        float b2r = __shfl_xor(ur[ff][2], 63), b2i = __shfl_xor(ui[ff][2], 63);
        float b3r = __shfl_xor(ur[ff][1], 63), b3i = __shfl_xor(ui[ff][1], 63);
        float b0r = __shfl(ur[ff][0], l0), b0i = __shfl(ui[ff][0], l0);
        float sp[4];
        #define UNP(J, ar, ai, br, bi, twr, twi)                        \
        {                                                               \
            float Er = 0.5f * (ar + br), Ei = 0.5f * (ai - bi);         \
            float Or = 0.5f * (ai + bi), Oi = 0.5f * (br - ar);         \
            float Xr = Er + twr * Or - twi * Oi;                        \
            float Xi = Ei + twr * Oi + twi * Or;                        \
            sp[J] = Xr * Xr + Xi * Xi;                                  \
        }
        UNP(0, ur[ff][0], ui[ff][0], b0r, b0i, wc.x, wn.x)
        UNP(1, ur[ff][1], ui[ff][1], b1r, b1i, wc.y, wn.y)
        UNP(2, ur[ff][2], ui[ff][2], b2r, b2i, wc.z, wn.z)
        UNP(3, ur[ff][3], ui[ff][3], b3r, b3i, wc.w, wn.w)
        #undef UNP
        ((float4*)s_spec[w * 2 + ff])[m + (m >> 3)] = make_float4(sp[0], sp[1], sp[2], sp[3]);
        if (l == 0) {
            float d = ur[ff][0] - ui[ff][0];  // X[256] = Re(Z0) - Im(Z0)
            s_spec[w * 2 + ff][specIdx(256)] = d * d;
        }
    }

    // sparse mel projection (wave-private spec; no barrier needed)
    const int q = l & 3;
    #pragma unroll
    for (int ff = 0; ff < 2; ++ff) {
        const int fr = w * 2 + ff;
        const size_t outbase = (size_t)(b * F + fidx[ff]) * NMEL;
        // narrow mels 0..63: one lane per mel
        float mv0;
        {
            int mel = l;
            int k0 = s_k0[mel], len = s_len[mel];
            float acc = 0.0f;
            for (int i = 0; i < len; ++i)
                acc = fmaf(s_spec[fr][specIdx(k0 + i)], s_wgt[i * NMEL + mel], acc);
            mv0 = __logf(fmaxf(acc, MEL_FLOOR));
            if (live[ff]) mel_out[outbase + l] = mv0;
        }
        // wide mels 64..79: 4 lanes per mel, DPP-combine
        float mv1 = 0.0f;
        {
            int mel = 64 + (l >> 2);
            int k0 = s_k0[mel], len = s_len[mel];
            float acc = 0.0f;
            for (int i = q; i < len; i += 4)
                acc = fmaf(s_spec[fr][specIdx(k0 + i)], s_wgt[i * NMEL + mel], acc);
            acc += dppf<DPP_XOR1>(acc);
            acc += dppf<DPP_XOR2>(acc);
            if (q == 0) {
                mv1 = __logf(fmaxf(acc, MEL_FLOOR));
                if (live[ff]) mel_out[outbase + mel] = mv1;
            }
        }
        // stats stage (values only; squares computed at reduction)
        s_ss[fr][l] = live[ff] ? mv0 : 0.0f;
        if (q == 0) s_ss[fr][64 + (l >> 2)] = live[ff] ? mv1 : 0.0f;
    }
    __syncthreads();
    if (t < 80) {
        float s = 0.0f, s2 = 0.0f;
        #pragma unroll
        for (int i = 0; i < FRB; ++i) {
            float v = s_ss[i][t];
            s += v;
            s2 += v * v;
        }
        if (partMode) {
            ws[WS_PART + (size_t)bid * 160 + t] = s;
            ws[WS_PART + (size_t)bid * 160 + 80 + t] = s2;
        } else {
            atomicAdd(&ws[WS_ACC + b * 160 + t], s);
            atomicAdd(&ws[WS_ACC + b * 160 + 80 + t], s2);
        }
    }
}

// ---------------- Kernel 2: finalize stats (parallel over 8 rows) ----------------
__global__ __launch_bounds__(640) void stats_final_kernel(float* __restrict__ ws, int partMode)
{
    const int b = blockIdx.x;
    const int m = threadIdx.x;   // 0..79
    const int r = threadIdx.y;   // 0..7
    __shared__ float shs[8][NMEL], shs2[8][NMEL];
    float s = 0.0f, s2 = 0.0f;
    if (partMode) {
        for (int c = r; c < BPB; c += 8) {
            const float* base = ws + WS_PART + (size_t)(b * BPB + c) * 160;
            s += base[m];
            s2 += base[80 + m];
        }
    }
    shs[r][m] = s; shs2[r][m] = s2;
    __syncthreads();
    if (r == 0) {
        double ds = 0.0, ds2 = 0.0;
        if (partMode) {
            #pragma unroll
            for (int i = 0; i < 8; ++i) { ds += (double)shs[i][m]; ds2 += (double)shs2[i][m]; }
        } else {
            ds = (double)ws[WS_ACC + b * 160 + m];
            ds2 = (double)ws[WS_ACC + b * 160 + 80 + m];
        }
        double mean = ds / (double)F;
        double var = (ds2 - ds * ds / (double)F) / (double)(F - 1);
        ws[WS_STAT + b * 160 + m] = (float)mean;
        ws[WS_STAT + b * 160 + 80 + m] = (float)(1.0 / sqrt(var + 1e-7));
    }
}

// ---------------- Kernel 3: normalize (float4) + mask ----------------
__global__ __launch_bounds__(256) void norm_mask_kernel(
    float* __restrict__ out, const float* __restrict__ ws)
{
    const float* stat = ws + WS_STAT;
    const int total4 = (B * F * NMEL) / 4;
    const int stride = gridDim.x * blockDim.x;
    float4* out4 = (float4*)out;
    for (int e4 = blockIdx.x * blockDim.x + threadIdx.x; e4 < total4; e4 += stride) {
        int e = e4 * 4;
        int b = e / (F * NMEL);
        int m = e % NMEL;
        const float* sb = stat + b * 160;
        float4 v = out4[e4];
        v.x = (v.x - sb[m + 0]) * sb[80 + m + 0];
        v.y = (v.y - sb[m + 1]) * sb[80 + m + 1];
        v.z = (v.z - sb[m + 2]) * sb[80 + m + 2];
        v.w = (v.w - sb[m + 3]) * sb[80 + m + 3];
        out4[e4] = v;
    }
    const int nmask = B * (F / 2);
    float* mask = out + (size_t)B * F * NMEL;
    for (int e = blockIdx.x * blockDim.x + threadIdx.x; e < nmask; e += stride)
        mask[e] = 1.0f;
}

extern "C" void kernel_launch(void* const* d_in, const int* in_sizes, int n_in,
                              void* d_out, int out_size, void* d_ws, size_t ws_size,
                              hipStream_t stream) {
    const float* wav = (const float*)d_in[0];
    const float* fil = (const float*)d_in[1];
    const float* win = (const float*)d_in[2];
    float* out = (float*)d_out;
    float* ws = (float*)d_ws;

    const int partMode = (ws_size >= WS_NEED_PART) ? 1 : 0;

    setup_kernel<<<1, 256, 0, stream>>>(fil, ws);
    frame_logmel_kernel<<<NBLK, 512, 0, stream>>>(wav, win, ws, out, partMode);
    stats_final_kernel<<<B, dim3(NMEL, 8), 0, stream>>>(ws, partMode);
    norm_mask_kernel<<<2048, 256, 0, stream>>>(out, ws);
}